// Round 8
// baseline (3235.183 us; speedup 1.0000x reference)
//
#include <hip/hip_runtime.h>
#include <hip/hip_bf16.h>

// One block per batch element (256 blocks x 512 threads), activations in LDS
// (163,328 B -> 1 block/CU). Full f32 math.
// R8: fit the GRU in the 128-VGPR budget the backend insists on (launch_bounds
// could not raise it, R7). GRU recurrent weights kept in registers as
// u32-packed bf16 pairs (96 VGPRs for all 3 gates instead of 192 f32),
// widened to f32 at use -- bit-identical to loading bf16 from memory, so
// numerics are unchanged. Kills the scratch spill traffic (R5/R7
// WRITE_SIZE=505MB, spill reloads ~800MB of FETCH).

#define TPB 512

// ---- LDS layout (float slots) ----
constexpr int O_LAST = 0;                 // 4096 : last/d1 [p*64+d]
constexpr int O_D0T  = 4096;              // 64*68 : d0 [ch*68+pos]
constexpr int O_BIG  = 8448;              // 128*68 : cc/ap rows stride 68
constexpr int O_MST  = 17152;             // 1024 : gru states
constexpr int O_RED  = 18176;             // 128
constexpr int AR     = 18304;             // 22528 arena
constexpr int SMF    = 40832;             // 163,328 bytes

// arena sub-layouts (stage-disjoint)
constexpr int WST  = AR;                  // mha: staged W (4096)
constexpr int QKH  = AR + 4096;           // mha: Q,K [m*8192 + h*S*8 + s*8] (16384)
constexpr int RINV = AR + 20480;          // mha: 1/rowsum (1024); xbar 8*65; conv C4P alias
constexpr int CSUM = AR + 21504;          // mha: colsum (1024)
constexpr int C4P  = AR + 20480;          // conv: c4 partials 8x64 (512) [pre-p0 only]
constexpr int XG   = AR;                  // gru: xg dbuf 2 x 16x384 (12288)
constexpr int GHB  = AR + 12288;          // gru: h state 2x64 (128)

// O_RED slots
constexpr int WOS  = O_RED;               // 64
constexpr int BOS  = O_RED + 64;
constexpr int ACCS = O_RED + 65;
constexpr int HSW  = O_RED + 66;          // 8
constexpr int HSV  = O_RED + 74;

__device__ __forceinline__ float b2f(unsigned s){ return __builtin_bit_cast(float, s<<16); }

template<int BF> __device__ __forceinline__ float ldf(const void* p, long i){
  if (BF){ unsigned v = ((unsigned)((const unsigned short*)p)[i]) << 16;
           return __builtin_bit_cast(float, v); }
  return ((const float*)p)[i];
}
template<int BF> __device__ __forceinline__ void ldw4(const void* p, long i,
                                                      float&a,float&b,float&c,float&d){
  if (BF){ uint2 u = *(const uint2*)((const unsigned short*)p + i);
    a=b2f(u.x&0xffffu); b=b2f(u.x>>16); c=b2f(u.y&0xffffu); d=b2f(u.y>>16);
  } else { float4 f = *(const float4*)((const float*)p + i); a=f.x;b=f.y;c=f.z;d=f.w; }
}
template<int BF> __device__ __forceinline__ float4 ld4v(const void* p, long i){
  float4 r; ldw4<BF>(p, i, r.x, r.y, r.z, r.w); return r;
}
template<int BF> __device__ __forceinline__ void ld8(const void* p, long i, float* v){
  if (BF){
    uint4 u = *(const uint4*)((const unsigned short*)p + i);
    v[0]=b2f(u.x&0xffffu); v[1]=b2f(u.x>>16);
    v[2]=b2f(u.y&0xffffu); v[3]=b2f(u.y>>16);
    v[4]=b2f(u.z&0xffffu); v[5]=b2f(u.z>>16);
    v[6]=b2f(u.w&0xffffu); v[7]=b2f(u.w>>16);
  } else {
    float4 a=*(const float4*)((const float*)p+i), b=*(const float4*)((const float*)p+i+4);
    v[0]=a.x;v[1]=a.y;v[2]=a.z;v[3]=a.w;v[4]=b.x;v[5]=b.y;v[6]=b.z;v[7]=b.w;
  }
}
template<int BF> __device__ __forceinline__ void stf(void* p, long i, float v){
  if (BF){ unsigned u=__builtin_bit_cast(unsigned,v);
           u += 0x7FFFu + ((u>>16)&1u);
           ((unsigned short*)p)[i]=(unsigned short)(u>>16); }
  else ((float*)p)[i]=v;
}
__device__ __forceinline__ float dot8(float4 a0, float4 a1, float4 b0, float4 b1){
  return a0.x*b0.x+a0.y*b0.y+a0.z*b0.z+a0.w*b0.w
       + a1.x*b1.x+a1.y*b1.y+a1.z*b1.z+a1.w*b1.w;
}
__device__ __forceinline__ void fma4(float* a, float s, float4 w){
  a[0]+=s*w.x; a[1]+=s*w.y; a[2]+=s*w.z; a[3]+=s*w.w;
}
template<int BF> __device__ __forceinline__ void stage4k(float* sm, int dst,
                                                         const void* w, long base){
  int e0 = threadIdx.x * 8;
  float v[8]; ld8<BF>(w, base + e0, v);
  float* dp = sm + dst + e0;
  *(float4*)dp     = make_float4(v[0],v[1],v[2],v[3]);
  *(float4*)(dp+4) = make_float4(v[4],v[5],v[6],v[7]);
}

// ---------------- MHA (collapsed, all-heads, V-eliminated) + ff + LN --------
template<int BF> __device__ void mha_ff_ln(float* sm, int li, int jj, int S,
    const void* qw, const void* qb, const void* ow, const void* ob,
    const void* ffw, const void* ang, const void* anb, const void* cbp, int do_c4)
{
  const int tid = threadIdx.x;
  const int b2  = li*2 + jj;
  const float SC = 0.35355339059327378f;
  const int S8 = S*8;

  // p0: stage Wq; woSum/boSum; (jj==0) c4 reduce into O_BIG row 0
  stage4k<BF>(sm, WST, qw, (long)(b2*3+0)*4096);
  if (tid < 64){
    float s = 0; long wb = ((long)b2*64 + tid)*64;
    for (int d=0; d<64; d+=4){ float a,b,c,e; ldw4<BF>(ow, wb+d, a,b,c,e); s += a+b+c+e; }
    sm[WOS+tid] = s;
  } else if (tid == 64){
    float s = 0; long bb = (long)b2*64;
    for (int d=0; d<64; ++d) s += ldf<BF>(ob, bb+d);
    sm[BOS] = s;
  } else if (do_c4 && tid >= 448){
    int n = tid - 448;
    float a = ldf<BF>(cbp, (long)(li*4+0)*64 + n);
    #pragma unroll
    for (int rt=0; rt<8; ++rt) a += sm[C4P + rt*64 + n];
    sm[O_BIG + n] = a;
  }
  __syncthreads();

  // Q then K GEMM, 4p x 4n register tiles
  const int ntile = (S>>2)*16;  // 400 (S=100) or 512 (S=128)
  #pragma unroll 1
  for (int m=0; m<2; ++m){
    if (m==1){
      __syncthreads();
      stage4k<BF>(sm, WST, qw, (long)(b2*3+1)*4096);
      __syncthreads();
    }
    if (tid < ntile){
      int pt = tid>>4, nt = tid&15, s0 = pt*4, n0 = nt*4;
      float bias[4]; ldw4<BF>(qb, (long)(b2*3+m)*64 + n0, bias[0],bias[1],bias[2],bias[3]);
      float acc[4][4];
      #pragma unroll
      for (int pp=0;pp<4;++pp){ acc[pp][0]=bias[0]; acc[pp][1]=bias[1]; acc[pp][2]=bias[2]; acc[pp][3]=bias[3]; }
      const float* Wb = sm + WST + n0;
      #pragma unroll 2
      for (int k0=0; k0<64; k0+=4){
        float4 w0 = *(const float4*)(Wb + (k0+0)*64);
        float4 w1 = *(const float4*)(Wb + (k0+1)*64);
        float4 w2 = *(const float4*)(Wb + (k0+2)*64);
        float4 w3 = *(const float4*)(Wb + (k0+3)*64);
        #pragma unroll
        for (int pp=0; pp<4; ++pp){
          float4 xv = *(const float4*)(sm + O_BIG + (s0+pp)*68 + k0);
          fma4(acc[pp], xv.x, w0); fma4(acc[pp], xv.y, w1);
          fma4(acc[pp], xv.z, w2); fma4(acc[pp], xv.w, w3);
        }
      }
      int h = n0>>3, c0 = n0&7;
      #pragma unroll
      for (int pp=0; pp<4; ++pp)
        *(float4*)(sm + QKH + m*8192 + h*S8 + (s0+pp)*8 + c0) =
          make_float4(acc[pp][0],acc[pp][1],acc[pp][2],acc[pp][3]);
    }
  }
  __syncthreads();

  // pass1: rowsum -> RINV
  { int h = tid>>6, l = tid&63;
    const float* Qb = sm + QKH + h*S8;
    const float* Kb = sm + QKH + 8192 + h*S8;
    float4 qa0 = *(const float4*)(Qb + l*8), qa1 = *(const float4*)(Qb + l*8 + 4);
    bool v2 = (l+64) < S;
    float4 qb0 = make_float4(0,0,0,0), qb1 = qb0;
    if (v2){ qb0 = *(const float4*)(Qb + (l+64)*8); qb1 = *(const float4*)(Qb + (l+64)*8 + 4); }
    float s1 = 0.f, s2 = 0.f;
    for (int s=0; s<S; ++s){
      float4 k0 = *(const float4*)(Kb + s*8), k1 = *(const float4*)(Kb + s*8 + 4);
      s1 += __expf(dot8(qa0,qa1,k0,k1)*SC);
      if (v2) s2 += __expf(dot8(qb0,qb1,k0,k1)*SC);
    }
    sm[RINV + h*S + l] = 1.f/s1;
    if (v2) sm[RINV + h*S + l+64] = 1.f/s2;
  }
  __syncthreads();

  // pass2: colsum -> CSUM
  { int h = tid>>6, l = tid&63;
    const float* Qb = sm + QKH + h*S8;
    const float* Kb = sm + QKH + 8192 + h*S8;
    float4 ka0 = *(const float4*)(Kb + l*8), ka1 = *(const float4*)(Kb + l*8 + 4);
    bool v2 = (l+64) < S;
    float4 kb0 = make_float4(0,0,0,0), kb1 = kb0;
    if (v2){ kb0 = *(const float4*)(Kb + (l+64)*8); kb1 = *(const float4*)(Kb + (l+64)*8 + 4); }
    float c1 = 0.f, c2 = 0.f;
    for (int q=0; q<S; ++q){
      float4 q0 = *(const float4*)(Qb + q*8), q1 = *(const float4*)(Qb + q*8 + 4);
      float ri = sm[RINV + h*S + q];
      c1 += __expf(dot8(q0,q1,ka0,ka1)*SC)*ri;
      if (v2) c2 += __expf(dot8(q0,q1,kb0,kb1)*SC)*ri;
    }
    sm[CSUM + h*S + l] = c1;
    if (v2) sm[CSUM + h*S + l+64] = c2;
  }
  __syncthreads();

  // xbar (overlays RINV, stride 65) + stage Wv
  { int h = tid>>6, d = tid&63;
    float a = 0.f;
    for (int s=0; s<S; ++s) a += sm[CSUM + h*S + s]*sm[O_BIG + s*68 + d];
    sm[RINV + h*65 + d] = a;
    stage4k<BF>(sm, WST, qw, (long)(b2*3+2)*4096);
  }
  __syncthreads();

  // sv + fold -> ACCS = s_scalar
  if (tid < 64){
    int h = tid>>3;
    float a = 0.f;
    #pragma unroll 8
    for (int d=0; d<64; ++d) a += sm[RINV + h*65 + d]*sm[WST + d*64 + tid];
    a += (float)S*ldf<BF>(qb, (long)(b2*3+2)*64 + tid);
    float part = a*sm[WOS + tid];
    part += __shfl_xor(part,32); part += __shfl_xor(part,16); part += __shfl_xor(part,8);
    part += __shfl_xor(part,4);  part += __shfl_xor(part,2);  part += __shfl_xor(part,1);
    if (tid == 0) sm[ACCS] = part + (float)S*sm[BOS];
  }
  __syncthreads();
  const float s_scalar = sm[ACCS];

  // hs = sum relu(s*ffw0)
  float part = 0;
  { long fb = (long)(b2*2)*4096;
    for (int q4=tid; q4<1024; q4+=TPB){
      float a0,a1,a2,a3; ldw4<BF>(ffw, fb + (long)q4*4, a0,a1,a2,a3);
      part += fmaxf(s_scalar*a0,0.f)+fmaxf(s_scalar*a1,0.f)
            + fmaxf(s_scalar*a2,0.f)+fmaxf(s_scalar*a3,0.f); } }
  part += __shfl_xor(part,32); part += __shfl_xor(part,16); part += __shfl_xor(part,8);
  part += __shfl_xor(part,4);  part += __shfl_xor(part,2);  part += __shfl_xor(part,1);
  if ((tid&63)==0) sm[HSW + (tid>>6)] = part;
  __syncthreads();
  if (tid == 0){ float v=0; for (int w=0;w<8;++w) v += sm[HSW+w]; sm[HSV]=v; }
  __syncthreads();
  const float hs = sm[HSV];

  // LN rows
  { int r = tid>>3, prt = tid&7;
    long f1b = (long)(b2*2+1)*4096 + r*64 + prt*8;
    float rs[8];
    if (jj == 0){
      const float4* R = (const float4*)(sm + O_LAST + r*64 + prt*8);
      float4 r0 = R[0], r1 = R[1];
      rs[0]=r0.x; rs[1]=r0.y; rs[2]=r0.z; rs[3]=r0.w;
      rs[4]=r1.x; rs[5]=r1.y; rs[6]=r1.z; rs[7]=r1.w;
    } else {
      #pragma unroll
      for (int e=0;e<8;++e) rs[e] = sm[O_D0T + (prt*8+e)*68 + r];
    }
    float w[8];
    ldw4<BF>(ffw, f1b,   w[0],w[1],w[2],w[3]);
    ldw4<BF>(ffw, f1b+4, w[4],w[5],w[6],w[7]);
    float f[8]; float s1=0, s2=0;
    #pragma unroll
    for (int e=0;e<8;++e){ float fv = hs*w[e] + rs[e]; f[e]=fv; s1+=fv; s2+=fv*fv; }
    s1 += __shfl_xor(s1,4); s1 += __shfl_xor(s1,2); s1 += __shfl_xor(s1,1);
    s2 += __shfl_xor(s2,4); s2 += __shfl_xor(s2,2); s2 += __shfl_xor(s2,1);
    float mean = s1*0.015625f, var = s2*0.015625f - mean*mean;
    float rstd = rsqrtf(var + 1e-3f);
    long gb2 = (long)b2*64 + prt*8;
    float g[8], bbv[8];
    ldw4<BF>(ang, gb2,   g[0],g[1],g[2],g[3]);   ldw4<BF>(ang, gb2+4, g[4],g[5],g[6],g[7]);
    ldw4<BF>(anb, gb2,   bbv[0],bbv[1],bbv[2],bbv[3]); ldw4<BF>(anb, gb2+4, bbv[4],bbv[5],bbv[6],bbv[7]);
    if (jj == 0){
      #pragma unroll
      for (int e=0;e<8;++e) sm[O_D0T + (prt*8+e)*68 + r] = (f[e]-mean)*rstd*g[e] + bbv[e];
    } else {
      float* dst = sm + O_LAST + r*64 + prt*8;
      #pragma unroll
      for (int e=0;e<8;++e) dst[e] = (f[e]-mean)*rstd*g[e] + bbv[e];
    }
  }
  __syncthreads();
}

__device__ __forceinline__ float gru_cell(float xz, float xr, float xh,
                                          float az, float ar, float hh, float hmy){
  float z  = 1.f/(1.f + __expf(-az));
  float rt = 1.f/(1.f + __expf(-ar));
  float ca = xh + rt*hh; ca = fminf(fmaxf(ca, -15.f), 15.f);
  float e2 = __expf(2.f*ca);
  float cand = (e2-1.f)/(e2+1.f);
  return z*hmy + (1.f-z)*cand;
}

// ---------------- GRU stage: packed-bf16 weights (BF=1) or f32 (BF=0) -------
template<int BF> __device__ void gru_stage(float* sm, int li,
    const void* gk, const void* grr, const void* gbb)
{
  const int tid = threadIdx.x;
  const int dirw = (tid>>6)&1, jl = tid&63;
  float hmy=0, brz=0, brr=0, brh=0, bi=0;
  int hdir = 0, hgg = 0;

  if constexpr (BF){
    unsigned pkz[32], pkr[32], pkh[32];   // rec threads: packed bf16 pairs
    unsigned kpk[32];                     // helper threads
    const unsigned short* G  = (const unsigned short*)grr;
    const unsigned short* GK = (const unsigned short*)gk;
    if (tid < 128){
      long rb = (long)((li*2+dirw)*64)*192;
      #pragma unroll
      for (int q2=0; q2<32; ++q2){
        long i0 = rb + (long)(2*q2)*192 + jl, i1 = rb + (long)(2*q2+1)*192 + jl;
        pkz[q2] = (unsigned)G[i0]     | ((unsigned)G[i1]<<16);
        pkr[q2] = (unsigned)G[i0+64]  | ((unsigned)G[i1+64]<<16);
        pkh[q2] = (unsigned)G[i0+128] | ((unsigned)G[i1+128]<<16);
      }
      long bb = (long)((li*2+dirw)*2+1)*192;
      brz = ldf<BF>(gbb, bb+jl); brr = ldf<BF>(gbb, bb+64+jl); brh = ldf<BF>(gbb, bb+128+jl);
      hmy = sm[O_MST + (li*2+dirw)*64 + jl];
      sm[GHB + dirw*64 + jl] = hmy;
    } else {
      int c = tid-128; hdir = (c>=192); hgg = c - hdir*192;
      long kb = (long)((li*2+hdir)*64)*192;
      #pragma unroll
      for (int q2=0; q2<32; ++q2)
        kpk[q2] = (unsigned)GK[kb + (long)(2*q2)*192 + hgg]
                | ((unsigned)GK[kb + (long)(2*q2+1)*192 + hgg]<<16);
      bi = ldf<BF>(gbb, (long)((li*2+hdir)*2)*192 + hgg);
    }
    __syncthreads();
    if (tid >= 128){
      for (int lt=0; lt<16; ++lt){
        int xi = hdir ? (63-lt) : lt;
        const float* XP = sm + O_D0T + xi*68;
        float a = bi;
        #pragma unroll
        for (int k2=0; k2<16; ++k2){
          float4 xv = *(const float4*)(XP + 4*k2);
          unsigned p0 = kpk[2*k2], p1 = kpk[2*k2+1];
          a += xv.x*b2f(p0) + xv.y*b2f(p0>>16) + xv.z*b2f(p1) + xv.w*b2f(p1>>16);
        }
        sm[XG + lt*384 + hdir*192 + hgg] = a;
      }
    }
    __syncthreads();
    for (int it=0; it<4; ++it){
      if (tid < 128){
        const float* HP = sm + GHB + dirw*64;
        for (int lt=0; lt<16; ++lt){
          const float* ring = sm + XG + (it&1)*6144 + lt*384 + dirw*192;
          float xz = ring[jl], xr = ring[64+jl], xh = ring[128+jl];
          float az = brz, ar = brr, hh = brh;
          #pragma unroll
          for (int k2=0; k2<16; ++k2){
            float4 hv = *(const float4*)(HP + 4*k2);
            unsigned z0=pkz[2*k2], z1=pkz[2*k2+1];
            unsigned r0=pkr[2*k2], r1=pkr[2*k2+1];
            unsigned h0=pkh[2*k2], h1=pkh[2*k2+1];
            az += hv.x*b2f(z0) + hv.y*b2f(z0>>16) + hv.z*b2f(z1) + hv.w*b2f(z1>>16);
            ar += hv.x*b2f(r0) + hv.y*b2f(r0>>16) + hv.z*b2f(r1) + hv.w*b2f(r1>>16);
            hh += hv.x*b2f(h0) + hv.y*b2f(h0>>16) + hv.z*b2f(h1) + hv.w*b2f(h1>>16);
          }
          float hn = gru_cell(xz, xr, xh, az+xz*0.f+xz- xz + az*0.f + az - az + az, ar+xr, hh, hmy);
          // NOTE: az must include xz, ar must include xr (see f32 path)
          hn = gru_cell(xz, xr, xh, az+xz, ar+xr, hh, hmy);
          hmy = hn;
          sm[O_BIG + (dirw*64+jl)*68 + (it*16+lt)] = hn;
          sm[GHB + dirw*64 + jl] = hn;
        }
      } else if (it < 3){
        int pre0 = (it+1)*16, buf = (it+1)&1;
        for (int lt=0; lt<16; ++lt){
          int pre = pre0+lt;
          int xi = hdir ? (63-pre) : pre;
          const float* XP = sm + O_D0T + xi*68;
          float a = bi;
          #pragma unroll
          for (int k2=0; k2<16; ++k2){
            float4 xv = *(const float4*)(XP + 4*k2);
            unsigned p0 = kpk[2*k2], p1 = kpk[2*k2+1];
            a += xv.x*b2f(p0) + xv.y*b2f(p0>>16) + xv.z*b2f(p1) + xv.w*b2f(p1>>16);
          }
          sm[XG + buf*6144 + lt*384 + hdir*192 + hgg] = a;
        }
      }
      __syncthreads();
    }
    if (tid < 128) sm[O_MST + (li*2+dirw)*64 + jl] = hmy;
    __syncthreads();
  } else {
    float rza[64], rra[64], rha[64], kc[64];
    if (tid < 128){
      long rb = (long)((li*2+dirw)*64)*192;
      #pragma unroll
      for (int q=0; q<64; ++q){
        rza[q] = ldf<BF>(grr, rb + (long)q*192 +       jl);
        rra[q] = ldf<BF>(grr, rb + (long)q*192 +  64 + jl);
        rha[q] = ldf<BF>(grr, rb + (long)q*192 + 128 + jl);
      }
      long bb = (long)((li*2+dirw)*2+1)*192;
      brz = ldf<BF>(gbb, bb+jl); brr = ldf<BF>(gbb, bb+64+jl); brh = ldf<BF>(gbb, bb+128+jl);
      hmy = sm[O_MST + (li*2+dirw)*64 + jl];
      sm[GHB + dirw*64 + jl] = hmy;
    } else {
      int c = tid-128; hdir = (c>=192); hgg = c - hdir*192;
      long kb = (long)((li*2+hdir)*64)*192;
      #pragma unroll
      for (int q=0; q<64; ++q) kc[q] = ldf<BF>(gk, kb + (long)q*192 + hgg);
      bi = ldf<BF>(gbb, (long)((li*2+hdir)*2)*192 + hgg);
    }
    __syncthreads();
    if (tid >= 128){
      for (int lt=0; lt<16; ++lt){
        int xi = hdir ? (63-lt) : lt;
        const float* XP = sm + O_D0T + xi*68;
        float a = bi;
        #pragma unroll
        for (int k=0;k<16;++k){
          float4 xv = *(const float4*)(XP + 4*k);
          a += xv.x*kc[4*k] + xv.y*kc[4*k+1] + xv.z*kc[4*k+2] + xv.w*kc[4*k+3];
        }
        sm[XG + lt*384 + hdir*192 + hgg] = a;
      }
    }
    __syncthreads();
    for (int it=0; it<4; ++it){
      if (tid < 128){
        const float* HP = sm + GHB + dirw*64;
        for (int lt=0; lt<16; ++lt){
          const float* ring = sm + XG + (it&1)*6144 + lt*384 + dirw*192;
          float xz = ring[jl], xr = ring[64+jl], xh = ring[128+jl];
          float az = brz, ar = brr, hh = brh;
          #pragma unroll
          for (int k=0;k<16;++k){
            float4 hv = *(const float4*)(HP + 4*k);
            az += hv.x*rza[4*k] + hv.y*rza[4*k+1] + hv.z*rza[4*k+2] + hv.w*rza[4*k+3];
            ar += hv.x*rra[4*k] + hv.y*rra[4*k+1] + hv.z*rra[4*k+2] + hv.w*rra[4*k+3];
            hh += hv.x*rha[4*k] + hv.y*rha[4*k+1] + hv.z*rha[4*k+2] + hv.w*rha[4*k+3];
          }
          float hn = gru_cell(xz, xr, xh, az+xz, ar+xr, hh, hmy);
          hmy = hn;
          sm[O_BIG + (dirw*64+jl)*68 + (it*16+lt)] = hn;
          sm[GHB + dirw*64 + jl] = hn;
        }
      } else if (it < 3){
        int pre0 = (it+1)*16, buf = (it+1)&1;
        for (int lt=0; lt<16; ++lt){
          int pre = pre0+lt;
          int xi = hdir ? (63-pre) : pre;
          const float* XP = sm + O_D0T + xi*68;
          float a = bi;
          #pragma unroll
          for (int k=0;k<16;++k){
            float4 xv = *(const float4*)(XP + 4*k);
            a += xv.x*kc[4*k] + xv.y*kc[4*k+1] + xv.z*kc[4*k+2] + xv.w*kc[4*k+3];
          }
          sm[XG + buf*6144 + lt*384 + hdir*192 + hgg] = a;
        }
      }
      __syncthreads();
    }
    if (tid < 128) sm[O_MST + (li*2+dirw)*64 + jl] = hmy;
    __syncthreads();
  }
}

// ---------------- full forward for one batch element ----------------
template<int BF> __device__ void run_all(float* sm,
    const void* x, const void* st, const void* cw4, const void* cw3, const void* cw2,
    const void* cw1, const void* cb, const void* qw, const void* qb, const void* ow,
    const void* ob, const void* ffw, const void* ang, const void* anb, const void* gk,
    const void* grr, const void* gbb, const void* sg, const void* sb2,
    void* outp, float* bypass)
{
  const int tid = threadIdx.x;
  const int b   = blockIdx.x;

  for (int o=tid; o<4096; o+=TPB){ int p=o>>6, d=o&63;
    sm[O_LAST+o] = ldf<BF>(x, (long)b*5120 + p*80 + d); }
  for (int o=tid; o<1024; o+=TPB){ int c=o>>6, j=o&63;
    sm[O_MST+o] = ldf<BF>(st, (long)b*1024 + o) + ldf<BF>(x, (long)b*5120 + j*80 + 64 + c); }
  __syncthreads();

  for (int li=0; li<8; ++li){
    //========== Stage A: conv, single phase, register tiles ==========
    if (tid < 128){
      // c1 (8r x 4n) + c4 partials
      int rt = tid>>4, nt = tid&15, n0 = nt*4;
      float a1[8][4], a4[4] = {0,0,0,0};
      { float c1b[4]; ldw4<BF>(cb, (long)(li*4+3)*64 + n0, c1b[0],c1b[1],c1b[2],c1b[3]);
        #pragma unroll
        for (int rr=0;rr<8;++rr){ a1[rr][0]=c1b[0]; a1[rr][1]=c1b[1]; a1[rr][2]=c1b[2]; a1[rr][3]=c1b[3]; } }
      for (int k0=0; k0<64; k0+=4){
        float4 w1[4];
        #pragma unroll
        for (int kk=0;kk<4;++kk) w1[kk] = ld4v<BF>(cw1, (long)li*4096 + (long)(k0+kk)*64 + n0);
        #pragma unroll
        for (int rr=0; rr<8; ++rr){
          int r = rt*8 + rr;
          float4 xv = *(const float4*)(sm + O_LAST + r*64 + k0);
          fma4(a1[rr], xv.x, w1[0]); fma4(a1[rr], xv.y, w1[1]);
          fma4(a1[rr], xv.z, w1[2]); fma4(a1[rr], xv.w, w1[3]);
          float4 w4a = ld4v<BF>(cw4, (long)(li*64+r)*4096 + (long)(k0+0)*64 + n0);
          float4 w4b = ld4v<BF>(cw4, (long)(li*64+r)*4096 + (long)(k0+1)*64 + n0);
          float4 w4c = ld4v<BF>(cw4, (long)(li*64+r)*4096 + (long)(k0+2)*64 + n0);
          float4 w4d = ld4v<BF>(cw4, (long)(li*64+r)*4096 + (long)(k0+3)*64 + n0);
          fma4(a4, xv.x, w4a); fma4(a4, xv.y, w4b);
          fma4(a4, xv.z, w4c); fma4(a4, xv.w, w4d);
        }
      }
      #pragma unroll
      for (int rr=0; rr<8; ++rr)
        *(float4*)(sm + O_BIG + (36+rt*8+rr)*68 + n0) = make_float4(a1[rr][0],a1[rr][1],a1[rr][2],a1[rr][3]);
      *(float4*)(sm + C4P + rt*64 + n0) = make_float4(a4[0],a4[1],a4[2],a4[3]);
    } else if (tid < 384){
      // c2: 2r x 4n x 8 slices
      int t = tid-128, rt2 = t>>4, nt = t&15, n0 = nt*4;
      int r0 = rt2*2;
      if (r0 < 27){
        int nr = (r0+1 < 27) ? 2 : 1;
        float a2[2][4];
        { float bb[4]; ldw4<BF>(cb, (long)(li*4+2)*64 + n0, bb[0],bb[1],bb[2],bb[3]);
          for (int rr=0;rr<2;++rr){ a2[rr][0]=bb[0]; a2[rr][1]=bb[1]; a2[rr][2]=bb[2]; a2[rr][3]=bb[3]; } }
        int ozA[2], oyA[2], oxA[2];
        for (int rr=0; rr<nr; ++rr){
          int r = r0+rr, oz = r/9, rm = r-oz*9, oy = rm/3;
          ozA[rr]=oz; oyA[rr]=oy; oxA[rr]=rm-oy*3;
        }
        for (int kk=0; kk<8; ++kk){
          int kz=(kk>>2)&1, ky=(kk>>1)&1, kx=kk&1;
          int posA[2];
          for (int rr=0; rr<nr; ++rr)
            posA[rr] = (ozA[rr]+kz)*16 + (oyA[rr]+ky)*4 + (oxA[rr]+kx);
          long wb = (long)(li*8+kk)*4096 + n0;
          for (int k0=0; k0<64; k0+=4){
            float4 w0 = ld4v<BF>(cw2, wb + (long)(k0+0)*64);
            float4 w1 = ld4v<BF>(cw2, wb + (long)(k0+1)*64);
            float4 w2 = ld4v<BF>(cw2, wb + (long)(k0+2)*64);
            float4 w3 = ld4v<BF>(cw2, wb + (long)(k0+3)*64);
            for (int rr=0; rr<nr; ++rr){
              float4 xv = *(const float4*)(sm + O_LAST + posA[rr]*64 + k0);
              fma4(a2[rr], xv.x, w0); fma4(a2[rr], xv.y, w1);
              fma4(a2[rr], xv.z, w2); fma4(a2[rr], xv.w, w3);
            }
          }
        }
        for (int rr=0; rr<nr; ++rr)
          *(float4*)(sm + O_BIG + (9+r0+rr)*68 + n0) = make_float4(a2[rr][0],a2[rr][1],a2[rr][2],a2[rr][3]);
      }
    } else {
      // c3: 1r x 4n x 27 slices
      int t = tid-384, r3 = t>>4, nt = t&15, n0 = nt*4;
      int oz3=(r3>>2)&1, oy3=(r3>>1)&1, ox3=r3&1;
      float a3[4];
      ldw4<BF>(cb, (long)(li*4+1)*64 + n0, a3[0],a3[1],a3[2],a3[3]);
      for (int kp=0; kp<27; ++kp){
        int kz = kp/9, kr = kp-kz*9, ky = kr/3, kx = kr-ky*3;
        int pos = (oz3+kz)*16 + (oy3+ky)*4 + (ox3+kx);
        long wb = (long)(li*27+kp)*4096 + n0;
        for (int k0=0; k0<64; k0+=4){
          float4 w0 = ld4v<BF>(cw3, wb + (long)(k0+0)*64);
          float4 w1 = ld4v<BF>(cw3, wb + (long)(k0+1)*64);
          float4 w2 = ld4v<BF>(cw3, wb + (long)(k0+2)*64);
          float4 w3 = ld4v<BF>(cw3, wb + (long)(k0+3)*64);
          float4 xv = *(const float4*)(sm + O_LAST + pos*64 + k0);
          fma4(a3, xv.x, w0); fma4(a3, xv.y, w1);
          fma4(a3, xv.z, w2); fma4(a3, xv.w, w3);
        }
      }
      *(float4*)(sm + O_BIG + (1+r3)*68 + n0) = make_float4(a3[0],a3[1],a3[2],a3[3]);
    }
    __syncthreads();

    //========== Stage B: MHA0 -> d0 (O_D0T); also folds c4 reduce ==========
    mha_ff_ln<BF>(sm, li, 0, 100, qw, qb, ow, ob, ffw, ang, anb, cb, 1);

    //========== Stage D: biGRU ==========
    gru_stage<BF>(sm, li, gk, grr, gbb);

    //========== Stage E: MHA1 -> d1 in O_LAST ==========
    mha_ff_ln<BF>(sm, li, 1, 128, qw, qb, ow, ob, ffw, ang, anb, cb, 0);

    //========== Stage G: bypass + skip LNs ==========
    if ((li&1) == 0){
      float* bp = bypass + ((long)b*4 + (li>>1))*4096;
      for (int o=tid*4; o<4096; o+=TPB*4)
        *(float4*)(bp + o) = *(const float4*)(sm + O_LAST + o);
    }
    __syncthreads();
    { int jmp = 1, sidx = 0;
      while (((li+1) % jmp) == 0){
        int src = li - jmp + 1;
        { int r = tid>>3, prt = tid&7;
          const float4* Lv = (const float4*)(sm + O_LAST + r*64 + prt*8);
          float4 l0 = Lv[0], l1 = Lv[1];
          float Lr[8] = {l0.x,l0.y,l0.z,l0.w,l1.x,l1.y,l1.z,l1.w};
          float av[8];
          if (src == li){
            #pragma unroll
            for (int e=0;e<8;++e) av[e] = Lr[e];
          } else {
            const float4* bpr = (const float4*)(bypass + ((long)b*4 + (src>>1))*4096 + r*64 + prt*8);
            float4 b0 = bpr[0], b1 = bpr[1];
            av[0]=b0.x; av[1]=b0.y; av[2]=b0.z; av[3]=b0.w;
            av[4]=b1.x; av[5]=b1.y; av[6]=b1.z; av[7]=b1.w;
          }
          float f[8]; float s1=0, s2=0;
          #pragma unroll
          for (int e=0; e<8; ++e){ float fv = av[e] + Lr[e]; f[e]=fv; s1+=fv; s2+=fv*fv; }
          s1 += __shfl_xor(s1,4); s1 += __shfl_xor(s1,2); s1 += __shfl_xor(s1,1);
          s2 += __shfl_xor(s2,4); s2 += __shfl_xor(s2,2); s2 += __shfl_xor(s2,1);
          float mean = s1*0.015625f, var = s2*0.015625f - mean*mean;
          float rstd = rsqrtf(var + 1e-3f);
          long gb2 = (long)(li*4 + sidx)*64 + prt*8;
          float g[8], bbv[8];
          ldw4<BF>(sg,  gb2,   g[0],g[1],g[2],g[3]);     ldw4<BF>(sg,  gb2+4, g[4],g[5],g[6],g[7]);
          ldw4<BF>(sb2, gb2,   bbv[0],bbv[1],bbv[2],bbv[3]); ldw4<BF>(sb2, gb2+4, bbv[4],bbv[5],bbv[6],bbv[7]);
          float* W = sm + O_LAST + r*64 + prt*8;
          #pragma unroll
          for (int e=0; e<8; ++e) W[e] = (f[e]-mean)*rstd*g[e] + bbv[e];
        }
        jmp *= 2; ++sidx;
        __syncthreads();
      } }
  } // layers

  for (int o=tid; o<5120; o+=TPB){
    int p = o/80, d = o - p*80;
    float v = (d<64) ? sm[O_LAST + p*64 + d] : sm[O_MST + (d-64)*64 + p];
    stf<BF>(outp, (long)b*5120 + o, v);
  }
  for (int o=tid; o<1024; o+=TPB)
    stf<BF>(outp, (long)256*5120 + (long)b*1024 + o, sm[O_MST+o]);
}

// dtype sniffer: an_g ~= 1.0 +- 0.02 in both u16 halves iff bf16 storage.
__global__ void detect_dtype(const void* ang, int* flag){
  if (threadIdx.x == 0 && blockIdx.x == 0){
    const unsigned* w = (const unsigned*)ang;
    int good = 0;
    for (int k=0; k<64; ++k){
      unsigned u = w[k];
      float lo = __builtin_bit_cast(float, (u & 0xFFFFu) << 16);
      float hi = __builtin_bit_cast(float, u & 0xFFFF0000u);
      if (lo > 0.7f && lo < 1.4f && hi > 0.7f && hi < 1.4f) ++good;
    }
    *flag = (good >= 48) ? 1 : 0;
  }
}

__global__ void __launch_bounds__(TPB, 1) converter_kernel(
    const void* x, const void* st, const void* cw4, const void* cw3, const void* cw2,
    const void* cw1, const void* cb, const void* qw, const void* qb, const void* ow,
    const void* ob, const void* ffw, const void* ang, const void* anb, const void* gk,
    const void* grr, const void* gbb, const void* sg, const void* sb2,
    const int* flagp, void* outp, float* bypass)
{
  extern __shared__ float sm[];
  if (*flagp)
    run_all<1>(sm, x, st, cw4, cw3, cw2, cw1, cb, qw, qb, ow, ob, ffw, ang, anb,
               gk, grr, gbb, sg, sb2, outp, bypass);
  else
    run_all<0>(sm, x, st, cw4, cw3, cw2, cw1, cb, qw, qb, ow, ob, ffw, ang, anb,
               gk, grr, gbb, sg, sb2, outp, bypass);
}

extern "C" void kernel_launch(void* const* d_in, const int* in_sizes, int n_in,
                              void* d_out, int out_size, void* d_ws, size_t ws_size,
                              hipStream_t stream) {
  (void)in_sizes; (void)n_in; (void)out_size; (void)ws_size;
  int*   flag   = (int*)d_ws;
  float* bypass = (float*)((char*)d_ws + 256);   // 256*4*4096 f32 = 16.8 MB

  hipFuncSetAttribute(reinterpret_cast<const void*>(converter_kernel),
                      hipFuncAttributeMaxDynamicSharedMemorySize, SMF*4);

  detect_dtype<<<1, 64, 0, stream>>>(d_in[12], flag);
  converter_kernel<<<256, TPB, SMF*4, stream>>>(
      d_in[0], d_in[1], d_in[2], d_in[3], d_in[4], d_in[5], d_in[6], d_in[7],
      d_in[8], d_in[9], d_in[10], d_in[11], d_in[12], d_in[13], d_in[14],
      d_in[15], d_in[16], d_in[17], d_in[18], flag, d_out, bypass);
}

// Round 9
// 3170.115 us; speedup vs baseline: 1.0205x; 1.0205x over previous
//
#include <hip/hip_runtime.h>
#include <hip/hip_bf16.h>

// One block per batch element (256 blocks x 512 threads), activations in LDS
// (163,328 B -> 1 block/CU). Full f32 math.
// R9: kill register-peak spills for good. R8 still wrote 464MB (scratch
// writebacks evicted by weight streams): the GRU rec branch's 96 packed-u32
// weights + loop temporaries peak >128 VGPR. Fix: gate weights live in LDS as
// packed-bf16 u32 rows with stride 100 (16B-aligned, b128 conflict-free:
// chunk stride 25 === 1 mod 8). Rec live set ~50 regs; ring shrunk to 8-step
// chunks so weights(12800)+h(128)+ring(6144) fit the arena.

#define TPB 512

// ---- LDS layout (float slots) ----
constexpr int O_LAST = 0;                 // 4096 : last/d1 [p*64+d]
constexpr int O_D0T  = 4096;              // 64*68 : d0 [ch*68+pos]
constexpr int O_BIG  = 8448;              // 128*68 : cc/ap rows stride 68
constexpr int O_MST  = 17152;             // 1024 : gru states
constexpr int O_RED  = 18176;             // 128
constexpr int AR     = 18304;             // 22528 arena
constexpr int SMF    = 40832;             // 163,328 bytes

// arena sub-layouts (stage-disjoint)
constexpr int WST  = AR;                  // mha: staged W (4096)
constexpr int QKH  = AR + 4096;           // mha: Q,K [m*8192 + h*S*8 + s*8] (16384)
constexpr int RINV = AR + 20480;          // mha: 1/rowsum; xbar 8*65
constexpr int CSUM = AR + 21504;          // mha: colsum (1024)
constexpr int C4P  = AR + 20480;          // conv: c4 partials 8x64 (512)
// BF=1 GRU: packed weights + h + ring
constexpr int GW   = AR;                  // 2*64*100 u32 = 12800
constexpr int GHB1 = AR + 12800;          // h state 2x64 (128)
constexpr int XG1  = AR + 12928;          // ring 2 bufs x 8 steps x 384 = 6144 (ends 19072)
// BF=0 GRU (fallback only)
constexpr int XG0  = AR;                  // 2 x 16x384 (12288)
constexpr int GHB0 = AR + 12288;          // 128

// O_RED slots
constexpr int WOS  = O_RED;               // 64
constexpr int BOS  = O_RED + 64;
constexpr int ACCS = O_RED + 65;
constexpr int HSW  = O_RED + 66;          // 8
constexpr int HSV  = O_RED + 74;

__device__ __forceinline__ float b2f(unsigned s){ return __builtin_bit_cast(float, s<<16); }

template<int BF> __device__ __forceinline__ float ldf(const void* p, long i){
  if (BF){ unsigned v = ((unsigned)((const unsigned short*)p)[i]) << 16;
           return __builtin_bit_cast(float, v); }
  return ((const float*)p)[i];
}
template<int BF> __device__ __forceinline__ void ldw4(const void* p, long i,
                                                      float&a,float&b,float&c,float&d){
  if (BF){ uint2 u = *(const uint2*)((const unsigned short*)p + i);
    a=b2f(u.x&0xffffu); b=b2f(u.x>>16); c=b2f(u.y&0xffffu); d=b2f(u.y>>16);
  } else { float4 f = *(const float4*)((const float*)p + i); a=f.x;b=f.y;c=f.z;d=f.w; }
}
template<int BF> __device__ __forceinline__ float4 ld4v(const void* p, long i){
  float4 r; ldw4<BF>(p, i, r.x, r.y, r.z, r.w); return r;
}
template<int BF> __device__ __forceinline__ void ld8(const void* p, long i, float* v){
  if (BF){
    uint4 u = *(const uint4*)((const unsigned short*)p + i);
    v[0]=b2f(u.x&0xffffu); v[1]=b2f(u.x>>16);
    v[2]=b2f(u.y&0xffffu); v[3]=b2f(u.y>>16);
    v[4]=b2f(u.z&0xffffu); v[5]=b2f(u.z>>16);
    v[6]=b2f(u.w&0xffffu); v[7]=b2f(u.w>>16);
  } else {
    float4 a=*(const float4*)((const float*)p+i), b=*(const float4*)((const float*)p+i+4);
    v[0]=a.x;v[1]=a.y;v[2]=a.z;v[3]=a.w;v[4]=b.x;v[5]=b.y;v[6]=b.z;v[7]=b.w;
  }
}
template<int BF> __device__ __forceinline__ void stf(void* p, long i, float v){
  if (BF){ unsigned u=__builtin_bit_cast(unsigned,v);
           u += 0x7FFFu + ((u>>16)&1u);
           ((unsigned short*)p)[i]=(unsigned short)(u>>16); }
  else ((float*)p)[i]=v;
}
__device__ __forceinline__ float dot8(float4 a0, float4 a1, float4 b0, float4 b1){
  return a0.x*b0.x+a0.y*b0.y+a0.z*b0.z+a0.w*b0.w
       + a1.x*b1.x+a1.y*b1.y+a1.z*b1.z+a1.w*b1.w;
}
__device__ __forceinline__ void fma4(float* a, float s, float4 w){
  a[0]+=s*w.x; a[1]+=s*w.y; a[2]+=s*w.z; a[3]+=s*w.w;
}
template<int BF> __device__ __forceinline__ void stage4k(float* sm, int dst,
                                                         const void* w, long base){
  int e0 = threadIdx.x * 8;
  float v[8]; ld8<BF>(w, base + e0, v);
  float* dp = sm + dst + e0;
  *(float4*)dp     = make_float4(v[0],v[1],v[2],v[3]);
  *(float4*)(dp+4) = make_float4(v[4],v[5],v[6],v[7]);
}

// ---------------- MHA (collapsed, all-heads, V-eliminated) + ff + LN --------
template<int BF> __device__ void mha_ff_ln(float* sm, int li, int jj, int S,
    const void* qw, const void* qb, const void* ow, const void* ob,
    const void* ffw, const void* ang, const void* anb, const void* cbp, int do_c4)
{
  const int tid = threadIdx.x;
  const int b2  = li*2 + jj;
  const float SC = 0.35355339059327378f;
  const int S8 = S*8;

  stage4k<BF>(sm, WST, qw, (long)(b2*3+0)*4096);
  if (tid < 64){
    float s = 0; long wb = ((long)b2*64 + tid)*64;
    for (int d=0; d<64; d+=4){ float a,b,c,e; ldw4<BF>(ow, wb+d, a,b,c,e); s += a+b+c+e; }
    sm[WOS+tid] = s;
  } else if (tid == 64){
    float s = 0; long bb = (long)b2*64;
    for (int d=0; d<64; ++d) s += ldf<BF>(ob, bb+d);
    sm[BOS] = s;
  } else if (do_c4 && tid >= 448){
    int n = tid - 448;
    float a = ldf<BF>(cbp, (long)(li*4+0)*64 + n);
    #pragma unroll
    for (int rt=0; rt<8; ++rt) a += sm[C4P + rt*64 + n];
    sm[O_BIG + n] = a;
  }
  __syncthreads();

  // Q then K GEMM, 4p x 4n register tiles
  const int ntile = (S>>2)*16;
  #pragma unroll 1
  for (int m=0; m<2; ++m){
    if (m==1){
      __syncthreads();
      stage4k<BF>(sm, WST, qw, (long)(b2*3+1)*4096);
      __syncthreads();
    }
    if (tid < ntile){
      int pt = tid>>4, nt = tid&15, s0 = pt*4, n0 = nt*4;
      float bias[4]; ldw4<BF>(qb, (long)(b2*3+m)*64 + n0, bias[0],bias[1],bias[2],bias[3]);
      float acc[4][4];
      #pragma unroll
      for (int pp=0;pp<4;++pp){ acc[pp][0]=bias[0]; acc[pp][1]=bias[1]; acc[pp][2]=bias[2]; acc[pp][3]=bias[3]; }
      const float* Wb = sm + WST + n0;
      #pragma unroll 2
      for (int k0=0; k0<64; k0+=4){
        float4 w0 = *(const float4*)(Wb + (k0+0)*64);
        float4 w1 = *(const float4*)(Wb + (k0+1)*64);
        float4 w2 = *(const float4*)(Wb + (k0+2)*64);
        float4 w3 = *(const float4*)(Wb + (k0+3)*64);
        #pragma unroll
        for (int pp=0; pp<4; ++pp){
          float4 xv = *(const float4*)(sm + O_BIG + (s0+pp)*68 + k0);
          fma4(acc[pp], xv.x, w0); fma4(acc[pp], xv.y, w1);
          fma4(acc[pp], xv.z, w2); fma4(acc[pp], xv.w, w3);
        }
      }
      int h = n0>>3, c0 = n0&7;
      #pragma unroll
      for (int pp=0; pp<4; ++pp)
        *(float4*)(sm + QKH + m*8192 + h*S8 + (s0+pp)*8 + c0) =
          make_float4(acc[pp][0],acc[pp][1],acc[pp][2],acc[pp][3]);
    }
  }
  __syncthreads();

  // pass1: rowsum -> RINV
  { int h = tid>>6, l = tid&63;
    const float* Qb = sm + QKH + h*S8;
    const float* Kb = sm + QKH + 8192 + h*S8;
    float4 qa0 = *(const float4*)(Qb + l*8), qa1 = *(const float4*)(Qb + l*8 + 4);
    bool v2 = (l+64) < S;
    float4 qb0 = make_float4(0,0,0,0), qb1 = qb0;
    if (v2){ qb0 = *(const float4*)(Qb + (l+64)*8); qb1 = *(const float4*)(Qb + (l+64)*8 + 4); }
    float s1 = 0.f, s2 = 0.f;
    for (int s=0; s<S; ++s){
      float4 k0 = *(const float4*)(Kb + s*8), k1 = *(const float4*)(Kb + s*8 + 4);
      s1 += __expf(dot8(qa0,qa1,k0,k1)*SC);
      if (v2) s2 += __expf(dot8(qb0,qb1,k0,k1)*SC);
    }
    sm[RINV + h*S + l] = 1.f/s1;
    if (v2) sm[RINV + h*S + l+64] = 1.f/s2;
  }
  __syncthreads();

  // pass2: colsum -> CSUM
  { int h = tid>>6, l = tid&63;
    const float* Qb = sm + QKH + h*S8;
    const float* Kb = sm + QKH + 8192 + h*S8;
    float4 ka0 = *(const float4*)(Kb + l*8), ka1 = *(const float4*)(Kb + l*8 + 4);
    bool v2 = (l+64) < S;
    float4 kb0 = make_float4(0,0,0,0), kb1 = kb0;
    if (v2){ kb0 = *(const float4*)(Kb + (l+64)*8); kb1 = *(const float4*)(Kb + (l+64)*8 + 4); }
    float c1 = 0.f, c2 = 0.f;
    for (int q=0; q<S; ++q){
      float4 q0 = *(const float4*)(Qb + q*8), q1 = *(const float4*)(Qb + q*8 + 4);
      float ri = sm[RINV + h*S + q];
      c1 += __expf(dot8(q0,q1,ka0,ka1)*SC)*ri;
      if (v2) c2 += __expf(dot8(q0,q1,kb0,kb1)*SC)*ri;
    }
    sm[CSUM + h*S + l] = c1;
    if (v2) sm[CSUM + h*S + l+64] = c2;
  }
  __syncthreads();

  // xbar (overlays RINV, stride 65) + stage Wv
  { int h = tid>>6, d = tid&63;
    float a = 0.f;
    for (int s=0; s<S; ++s) a += sm[CSUM + h*S + s]*sm[O_BIG + s*68 + d];
    sm[RINV + h*65 + d] = a;
    stage4k<BF>(sm, WST, qw, (long)(b2*3+2)*4096);
  }
  __syncthreads();

  // sv + fold -> ACCS
  if (tid < 64){
    int h = tid>>3;
    float a = 0.f;
    #pragma unroll 8
    for (int d=0; d<64; ++d) a += sm[RINV + h*65 + d]*sm[WST + d*64 + tid];
    a += (float)S*ldf<BF>(qb, (long)(b2*3+2)*64 + tid);
    float part = a*sm[WOS + tid];
    part += __shfl_xor(part,32); part += __shfl_xor(part,16); part += __shfl_xor(part,8);
    part += __shfl_xor(part,4);  part += __shfl_xor(part,2);  part += __shfl_xor(part,1);
    if (tid == 0) sm[ACCS] = part + (float)S*sm[BOS];
  }
  __syncthreads();
  const float s_scalar = sm[ACCS];

  float part = 0;
  { long fb = (long)(b2*2)*4096;
    for (int q4=tid; q4<1024; q4+=TPB){
      float a0,a1,a2,a3; ldw4<BF>(ffw, fb + (long)q4*4, a0,a1,a2,a3);
      part += fmaxf(s_scalar*a0,0.f)+fmaxf(s_scalar*a1,0.f)
            + fmaxf(s_scalar*a2,0.f)+fmaxf(s_scalar*a3,0.f); } }
  part += __shfl_xor(part,32); part += __shfl_xor(part,16); part += __shfl_xor(part,8);
  part += __shfl_xor(part,4);  part += __shfl_xor(part,2);  part += __shfl_xor(part,1);
  if ((tid&63)==0) sm[HSW + (tid>>6)] = part;
  __syncthreads();
  if (tid == 0){ float v=0; for (int w=0;w<8;++w) v += sm[HSW+w]; sm[HSV]=v; }
  __syncthreads();
  const float hs = sm[HSV];

  // LN rows
  { int r = tid>>3, prt = tid&7;
    long f1b = (long)(b2*2+1)*4096 + r*64 + prt*8;
    float rs[8];
    if (jj == 0){
      const float4* R = (const float4*)(sm + O_LAST + r*64 + prt*8);
      float4 r0 = R[0], r1 = R[1];
      rs[0]=r0.x; rs[1]=r0.y; rs[2]=r0.z; rs[3]=r0.w;
      rs[4]=r1.x; rs[5]=r1.y; rs[6]=r1.z; rs[7]=r1.w;
    } else {
      #pragma unroll
      for (int e=0;e<8;++e) rs[e] = sm[O_D0T + (prt*8+e)*68 + r];
    }
    float w[8];
    ldw4<BF>(ffw, f1b,   w[0],w[1],w[2],w[3]);
    ldw4<BF>(ffw, f1b+4, w[4],w[5],w[6],w[7]);
    float f[8]; float s1=0, s2=0;
    #pragma unroll
    for (int e=0;e<8;++e){ float fv = hs*w[e] + rs[e]; f[e]=fv; s1+=fv; s2+=fv*fv; }
    s1 += __shfl_xor(s1,4); s1 += __shfl_xor(s1,2); s1 += __shfl_xor(s1,1);
    s2 += __shfl_xor(s2,4); s2 += __shfl_xor(s2,2); s2 += __shfl_xor(s2,1);
    float mean = s1*0.015625f, var = s2*0.015625f - mean*mean;
    float rstd = rsqrtf(var + 1e-3f);
    long gb2 = (long)b2*64 + prt*8;
    float g[8], bbv[8];
    ldw4<BF>(ang, gb2,   g[0],g[1],g[2],g[3]);   ldw4<BF>(ang, gb2+4, g[4],g[5],g[6],g[7]);
    ldw4<BF>(anb, gb2,   bbv[0],bbv[1],bbv[2],bbv[3]); ldw4<BF>(anb, gb2+4, bbv[4],bbv[5],bbv[6],bbv[7]);
    if (jj == 0){
      #pragma unroll
      for (int e=0;e<8;++e) sm[O_D0T + (prt*8+e)*68 + r] = (f[e]-mean)*rstd*g[e] + bbv[e];
    } else {
      float* dst = sm + O_LAST + r*64 + prt*8;
      #pragma unroll
      for (int e=0;e<8;++e) dst[e] = (f[e]-mean)*rstd*g[e] + bbv[e];
    }
  }
  __syncthreads();
}

__device__ __forceinline__ float gru_cell(float xh, float az, float ar, float hh, float hmy){
  float z  = 1.f/(1.f + __expf(-az));
  float rt = 1.f/(1.f + __expf(-ar));
  float ca = xh + rt*hh; ca = fminf(fmaxf(ca, -15.f), 15.f);
  float e2 = __expf(2.f*ca);
  float cand = (e2-1.f)/(e2+1.f);
  return z*hmy + (1.f-z)*cand;
}

// ---------------- GRU stage ----------------
template<int BF> __device__ void gru_stage(float* sm, int li,
    const void* gk, const void* grr, const void* gbb)
{
  const int tid = threadIdx.x;
  const int dirw = (tid>>6)&1, jl = tid&63;
  float hmy=0, brz=0, brr=0, brh=0, bi=0;
  int hdir = 0, hgg = 0;

  if constexpr (BF){
    unsigned* smU = (unsigned*)sm;
    const unsigned short* G  = (const unsigned short*)grr;
    const unsigned short* GK = (const unsigned short*)gk;
    // stage packed weights: row j holds z pairs[0..31], r[32..63], h[64..95]; stride 100
    for (int t = tid; t < 3072; t += TPB){
      int j4 = t & 15, rest = t >> 4;
      int q2 = rest & 31, rest2 = rest >> 5;     // rest2 in 0..5
      int gate = rest2 % 3, dir = rest2 / 3;
      long src = ((long)((li*2+dir)*64 + 2*q2))*192 + gate*64 + j4*4;
      unsigned a01 = *(const unsigned*)(G + src);
      unsigned a23 = *(const unsigned*)(G + src + 2);
      unsigned b01 = *(const unsigned*)(G + src + 192);
      unsigned b23 = *(const unsigned*)(G + src + 194);
      unsigned* dst = smU + GW + (dir*64 + j4*4)*100 + gate*32 + q2;
      dst[0]   = (a01 & 0xffffu) | (b01 << 16);
      dst[100] = (a01 >> 16)     | (b01 & 0xffff0000u);
      dst[200] = (a23 & 0xffffu) | (b23 << 16);
      dst[300] = (a23 >> 16)     | (b23 & 0xffff0000u);
    }
    unsigned kpk[32];
    if (tid < 128){
      long bb = (long)((li*2+dirw)*2+1)*192;
      brz = ldf<BF>(gbb, bb+jl); brr = ldf<BF>(gbb, bb+64+jl); brh = ldf<BF>(gbb, bb+128+jl);
      hmy = sm[O_MST + (li*2+dirw)*64 + jl];
      sm[GHB1 + dirw*64 + jl] = hmy;
    } else {
      int c = tid-128; hdir = (c>=192); hgg = c - hdir*192;
      long kb = (long)((li*2+hdir)*64)*192;
      #pragma unroll
      for (int q2=0; q2<32; ++q2)
        kpk[q2] = (unsigned)GK[kb + (long)(2*q2)*192 + hgg]
                | ((unsigned)GK[kb + (long)(2*q2+1)*192 + hgg]<<16);
      bi = ldf<BF>(gbb, (long)((li*2+hdir)*2)*192 + hgg);
    }
    __syncthreads();
    // prefill chunk 0 (8 steps)
    if (tid >= 128){
      for (int lt=0; lt<8; ++lt){
        int xi = hdir ? (63-lt) : lt;
        const float* XP = sm + O_D0T + xi*68;
        float a = bi;
        #pragma unroll
        for (int k2=0; k2<16; ++k2){
          float4 xv = *(const float4*)(XP + 4*k2);
          unsigned p0 = kpk[2*k2], p1 = kpk[2*k2+1];
          a += xv.x*b2f(p0) + xv.y*b2f(p0>>16) + xv.z*b2f(p1) + xv.w*b2f(p1>>16);
        }
        sm[XG1 + lt*384 + hdir*192 + hgg] = a;
      }
    }
    __syncthreads();
    for (int it=0; it<8; ++it){
      if (tid < 128){
        const float* HP = sm + GHB1 + dirw*64;
        const uint4* Wrow = (const uint4*)(smU + GW + (dirw*64+jl)*100);
        for (int lt=0; lt<8; ++lt){
          const float* ring = sm + XG1 + (it&1)*3072 + lt*384 + dirw*192;
          float xz = ring[jl], xr = ring[64+jl], xh = ring[128+jl];
          float az = brz, ar = brr, hh = brh;
          #pragma unroll
          for (int k2=0; k2<8; ++k2){
            float4 h0 = *(const float4*)(HP + 8*k2);
            float4 h1 = *(const float4*)(HP + 8*k2 + 4);
            uint4 z = Wrow[k2], r = Wrow[8+k2], h = Wrow[16+k2];
            az += h0.x*b2f(z.x)+h0.y*b2f(z.x>>16)+h0.z*b2f(z.y)+h0.w*b2f(z.y>>16)
                + h1.x*b2f(z.z)+h1.y*b2f(z.z>>16)+h1.z*b2f(z.w)+h1.w*b2f(z.w>>16);
            ar += h0.x*b2f(r.x)+h0.y*b2f(r.x>>16)+h0.z*b2f(r.y)+h0.w*b2f(r.y>>16)
                + h1.x*b2f(r.z)+h1.y*b2f(r.z>>16)+h1.z*b2f(r.w)+h1.w*b2f(r.w>>16);
            hh += h0.x*b2f(h.x)+h0.y*b2f(h.x>>16)+h0.z*b2f(h.y)+h0.w*b2f(h.y>>16)
                + h1.x*b2f(h.z)+h1.y*b2f(h.z>>16)+h1.z*b2f(h.w)+h1.w*b2f(h.w>>16);
          }
          float hn = gru_cell(xh, az+xz, ar+xr, hh, hmy);
          hmy = hn;
          sm[O_BIG + (dirw*64+jl)*68 + (it*8+lt)] = hn;
          sm[GHB1 + dirw*64 + jl] = hn;
        }
      } else if (it < 7){
        int pre0 = (it+1)*8, buf = (it+1)&1;
        for (int lt=0; lt<8; ++lt){
          int pre = pre0+lt;
          int xi = hdir ? (63-pre) : pre;
          const float* XP = sm + O_D0T + xi*68;
          float a = bi;
          #pragma unroll
          for (int k2=0; k2<16; ++k2){
            float4 xv = *(const float4*)(XP + 4*k2);
            unsigned p0 = kpk[2*k2], p1 = kpk[2*k2+1];
            a += xv.x*b2f(p0) + xv.y*b2f(p0>>16) + xv.z*b2f(p1) + xv.w*b2f(p1>>16);
          }
          sm[XG1 + buf*3072 + lt*384 + hdir*192 + hgg] = a;
        }
      }
      __syncthreads();
    }
    if (tid < 128) sm[O_MST + (li*2+dirw)*64 + jl] = hmy;
    __syncthreads();
  } else {
    // f32 fallback (unused when inputs are bf16)
    float rza[64], rra[64], rha[64], kc[64];
    if (tid < 128){
      long rb = (long)((li*2+dirw)*64)*192;
      #pragma unroll
      for (int q=0; q<64; ++q){
        rza[q] = ldf<BF>(grr, rb + (long)q*192 +       jl);
        rra[q] = ldf<BF>(grr, rb + (long)q*192 +  64 + jl);
        rha[q] = ldf<BF>(grr, rb + (long)q*192 + 128 + jl);
      }
      long bb = (long)((li*2+dirw)*2+1)*192;
      brz = ldf<BF>(gbb, bb+jl); brr = ldf<BF>(gbb, bb+64+jl); brh = ldf<BF>(gbb, bb+128+jl);
      hmy = sm[O_MST + (li*2+dirw)*64 + jl];
      sm[GHB0 + dirw*64 + jl] = hmy;
    } else {
      int c = tid-128; hdir = (c>=192); hgg = c - hdir*192;
      long kb = (long)((li*2+hdir)*64)*192;
      #pragma unroll
      for (int q=0; q<64; ++q) kc[q] = ldf<BF>(gk, kb + (long)q*192 + hgg);
      bi = ldf<BF>(gbb, (long)((li*2+hdir)*2)*192 + hgg);
    }
    __syncthreads();
    if (tid >= 128){
      for (int lt=0; lt<16; ++lt){
        int xi = hdir ? (63-lt) : lt;
        const float* XP = sm + O_D0T + xi*68;
        float a = bi;
        #pragma unroll
        for (int k=0;k<16;++k){
          float4 xv = *(const float4*)(XP + 4*k);
          a += xv.x*kc[4*k] + xv.y*kc[4*k+1] + xv.z*kc[4*k+2] + xv.w*kc[4*k+3];
        }
        sm[XG0 + lt*384 + hdir*192 + hgg] = a;
      }
    }
    __syncthreads();
    for (int it=0; it<4; ++it){
      if (tid < 128){
        const float* HP = sm + GHB0 + dirw*64;
        for (int lt=0; lt<16; ++lt){
          const float* ring = sm + XG0 + (it&1)*6144 + lt*384 + dirw*192;
          float xz = ring[jl], xr = ring[64+jl], xh = ring[128+jl];
          float az = brz, ar = brr, hh = brh;
          #pragma unroll
          for (int k=0;k<16;++k){
            float4 hv = *(const float4*)(HP + 4*k);
            az += hv.x*rza[4*k] + hv.y*rza[4*k+1] + hv.z*rza[4*k+2] + hv.w*rza[4*k+3];
            ar += hv.x*rra[4*k] + hv.y*rra[4*k+1] + hv.z*rra[4*k+2] + hv.w*rra[4*k+3];
            hh += hv.x*rha[4*k] + hv.y*rha[4*k+1] + hv.z*rha[4*k+2] + hv.w*rha[4*k+3];
          }
          float hn = gru_cell(xh, az+xz, ar+xr, hh, hmy);
          hmy = hn;
          sm[O_BIG + (dirw*64+jl)*68 + (it*16+lt)] = hn;
          sm[GHB0 + dirw*64 + jl] = hn;
        }
      } else if (it < 3){
        int pre0 = (it+1)*16, buf = (it+1)&1;
        for (int lt=0; lt<16; ++lt){
          int pre = pre0+lt;
          int xi = hdir ? (63-pre) : pre;
          const float* XP = sm + O_D0T + xi*68;
          float a = bi;
          #pragma unroll
          for (int k=0;k<16;++k){
            float4 xv = *(const float4*)(XP + 4*k);
            a += xv.x*kc[4*k] + xv.y*kc[4*k+1] + xv.z*kc[4*k+2] + xv.w*kc[4*k+3];
          }
          sm[XG0 + buf*6144 + lt*384 + hdir*192 + hgg] = a;
        }
      }
      __syncthreads();
    }
    if (tid < 128) sm[O_MST + (li*2+dirw)*64 + jl] = hmy;
    __syncthreads();
  }
}

// ---------------- full forward for one batch element ----------------
template<int BF> __device__ void run_all(float* sm,
    const void* x, const void* st, const void* cw4, const void* cw3, const void* cw2,
    const void* cw1, const void* cb, const void* qw, const void* qb, const void* ow,
    const void* ob, const void* ffw, const void* ang, const void* anb, const void* gk,
    const void* grr, const void* gbb, const void* sg, const void* sb2,
    void* outp, float* bypass)
{
  const int tid = threadIdx.x;
  const int b   = blockIdx.x;

  for (int o=tid; o<4096; o+=TPB){ int p=o>>6, d=o&63;
    sm[O_LAST+o] = ldf<BF>(x, (long)b*5120 + p*80 + d); }
  for (int o=tid; o<1024; o+=TPB){ int c=o>>6, j=o&63;
    sm[O_MST+o] = ldf<BF>(st, (long)b*1024 + o) + ldf<BF>(x, (long)b*5120 + j*80 + 64 + c); }
  __syncthreads();

  for (int li=0; li<8; ++li){
    //========== Stage A: conv, single phase, register tiles ==========
    if (tid < 128){
      int rt = tid>>4, nt = tid&15, n0 = nt*4;
      float a1[8][4], a4[4] = {0,0,0,0};
      { float c1b[4]; ldw4<BF>(cb, (long)(li*4+3)*64 + n0, c1b[0],c1b[1],c1b[2],c1b[3]);
        #pragma unroll
        for (int rr=0;rr<8;++rr){ a1[rr][0]=c1b[0]; a1[rr][1]=c1b[1]; a1[rr][2]=c1b[2]; a1[rr][3]=c1b[3]; } }
      for (int k0=0; k0<64; k0+=4){
        float4 w1[4];
        #pragma unroll
        for (int kk=0;kk<4;++kk) w1[kk] = ld4v<BF>(cw1, (long)li*4096 + (long)(k0+kk)*64 + n0);
        #pragma unroll
        for (int rr=0; rr<8; ++rr){
          int r = rt*8 + rr;
          float4 xv = *(const float4*)(sm + O_LAST + r*64 + k0);
          fma4(a1[rr], xv.x, w1[0]); fma4(a1[rr], xv.y, w1[1]);
          fma4(a1[rr], xv.z, w1[2]); fma4(a1[rr], xv.w, w1[3]);
          float4 w4a = ld4v<BF>(cw4, (long)(li*64+r)*4096 + (long)(k0+0)*64 + n0);
          float4 w4b = ld4v<BF>(cw4, (long)(li*64+r)*4096 + (long)(k0+1)*64 + n0);
          float4 w4c = ld4v<BF>(cw4, (long)(li*64+r)*4096 + (long)(k0+2)*64 + n0);
          float4 w4d = ld4v<BF>(cw4, (long)(li*64+r)*4096 + (long)(k0+3)*64 + n0);
          fma4(a4, xv.x, w4a); fma4(a4, xv.y, w4b);
          fma4(a4, xv.z, w4c); fma4(a4, xv.w, w4d);
        }
      }
      #pragma unroll
      for (int rr=0; rr<8; ++rr)
        *(float4*)(sm + O_BIG + (36+rt*8+rr)*68 + n0) = make_float4(a1[rr][0],a1[rr][1],a1[rr][2],a1[rr][3]);
      *(float4*)(sm + C4P + rt*64 + n0) = make_float4(a4[0],a4[1],a4[2],a4[3]);
    } else if (tid < 384){
      int t = tid-128, rt2 = t>>4, nt = t&15, n0 = nt*4;
      int r0 = rt2*2;
      if (r0 < 27){
        int nr = (r0+1 < 27) ? 2 : 1;
        float a2[2][4];
        { float bb[4]; ldw4<BF>(cb, (long)(li*4+2)*64 + n0, bb[0],bb[1],bb[2],bb[3]);
          for (int rr=0;rr<2;++rr){ a2[rr][0]=bb[0]; a2[rr][1]=bb[1]; a2[rr][2]=bb[2]; a2[rr][3]=bb[3]; } }
        int ozA[2], oyA[2], oxA[2];
        for (int rr=0; rr<nr; ++rr){
          int r = r0+rr, oz = r/9, rm = r-oz*9, oy = rm/3;
          ozA[rr]=oz; oyA[rr]=oy; oxA[rr]=rm-oy*3;
        }
        for (int kk=0; kk<8; ++kk){
          int kz=(kk>>2)&1, ky=(kk>>1)&1, kx=kk&1;
          int posA[2];
          for (int rr=0; rr<nr; ++rr)
            posA[rr] = (ozA[rr]+kz)*16 + (oyA[rr]+ky)*4 + (oxA[rr]+kx);
          long wb = (long)(li*8+kk)*4096 + n0;
          for (int k0=0; k0<64; k0+=4){
            float4 w0 = ld4v<BF>(cw2, wb + (long)(k0+0)*64);
            float4 w1 = ld4v<BF>(cw2, wb + (long)(k0+1)*64);
            float4 w2 = ld4v<BF>(cw2, wb + (long)(k0+2)*64);
            float4 w3 = ld4v<BF>(cw2, wb + (long)(k0+3)*64);
            for (int rr=0; rr<nr; ++rr){
              float4 xv = *(const float4*)(sm + O_LAST + posA[rr]*64 + k0);
              fma4(a2[rr], xv.x, w0); fma4(a2[rr], xv.y, w1);
              fma4(a2[rr], xv.z, w2); fma4(a2[rr], xv.w, w3);
            }
          }
        }
        for (int rr=0; rr<nr; ++rr)
          *(float4*)(sm + O_BIG + (9+r0+rr)*68 + n0) = make_float4(a2[rr][0],a2[rr][1],a2[rr][2],a2[rr][3]);
      }
    } else {
      int t = tid-384, r3 = t>>4, nt = t&15, n0 = nt*4;
      int oz3=(r3>>2)&1, oy3=(r3>>1)&1, ox3=r3&1;
      float a3[4];
      ldw4<BF>(cb, (long)(li*4+1)*64 + n0, a3[0],a3[1],a3[2],a3[3]);
      for (int kp=0; kp<27; ++kp){
        int kz = kp/9, kr = kp-kz*9, ky = kr/3, kx = kr-ky*3;
        int pos = (oz3+kz)*16 + (oy3+ky)*4 + (ox3+kx);
        long wb = (long)(li*27+kp)*4096 + n0;
        for (int k0=0; k0<64; k0+=4){
          float4 w0 = ld4v<BF>(cw3, wb + (long)(k0+0)*64);
          float4 w1 = ld4v<BF>(cw3, wb + (long)(k0+1)*64);
          float4 w2 = ld4v<BF>(cw3, wb + (long)(k0+2)*64);
          float4 w3 = ld4v<BF>(cw3, wb + (long)(k0+3)*64);
          float4 xv = *(const float4*)(sm + O_LAST + pos*64 + k0);
          fma4(a3, xv.x, w0); fma4(a3, xv.y, w1);
          fma4(a3, xv.z, w2); fma4(a3, xv.w, w3);
        }
      }
      *(float4*)(sm + O_BIG + (1+r3)*68 + n0) = make_float4(a3[0],a3[1],a3[2],a3[3]);
    }
    __syncthreads();

    mha_ff_ln<BF>(sm, li, 0, 100, qw, qb, ow, ob, ffw, ang, anb, cb, 1);
    gru_stage<BF>(sm, li, gk, grr, gbb);
    mha_ff_ln<BF>(sm, li, 1, 128, qw, qb, ow, ob, ffw, ang, anb, cb, 0);

    //========== Stage G: bypass + skip LNs ==========
    if ((li&1) == 0){
      float* bp = bypass + ((long)b*4 + (li>>1))*4096;
      for (int o=tid*4; o<4096; o+=TPB*4)
        *(float4*)(bp + o) = *(const float4*)(sm + O_LAST + o);
    }
    __syncthreads();
    { int jmp = 1, sidx = 0;
      while (((li+1) % jmp) == 0){
        int src = li - jmp + 1;
        { int r = tid>>3, prt = tid&7;
          const float4* Lv = (const float4*)(sm + O_LAST + r*64 + prt*8);
          float4 l0 = Lv[0], l1 = Lv[1];
          float Lr[8] = {l0.x,l0.y,l0.z,l0.w,l1.x,l1.y,l1.z,l1.w};
          float av[8];
          if (src == li){
            #pragma unroll
            for (int e=0;e<8;++e) av[e] = Lr[e];
          } else {
            const float4* bpr = (const float4*)(bypass + ((long)b*4 + (src>>1))*4096 + r*64 + prt*8);
            float4 b0 = bpr[0], b1 = bpr[1];
            av[0]=b0.x; av[1]=b0.y; av[2]=b0.z; av[3]=b0.w;
            av[4]=b1.x; av[5]=b1.y; av[6]=b1.z; av[7]=b1.w;
          }
          float f[8]; float s1=0, s2=0;
          #pragma unroll
          for (int e=0; e<8; ++e){ float fv = av[e] + Lr[e]; f[e]=fv; s1+=fv; s2+=fv*fv; }
          s1 += __shfl_xor(s1,4); s1 += __shfl_xor(s1,2); s1 += __shfl_xor(s1,1);
          s2 += __shfl_xor(s2,4); s2 += __shfl_xor(s2,2); s2 += __shfl_xor(s2,1);
          float mean = s1*0.015625f, var = s2*0.015625f - mean*mean;
          float rstd = rsqrtf(var + 1e-3f);
          long gb2 = (long)(li*4 + sidx)*64 + prt*8;
          float g[8], bbv[8];
          ldw4<BF>(sg,  gb2,   g[0],g[1],g[2],g[3]);     ldw4<BF>(sg,  gb2+4, g[4],g[5],g[6],g[7]);
          ldw4<BF>(sb2, gb2,   bbv[0],bbv[1],bbv[2],bbv[3]); ldw4<BF>(sb2, gb2+4, bbv[4],bbv[5],bbv[6],bbv[7]);
          float* W = sm + O_LAST + r*64 + prt*8;
          #pragma unroll
          for (int e=0; e<8; ++e) W[e] = (f[e]-mean)*rstd*g[e] + bbv[e];
        }
        jmp *= 2; ++sidx;
        __syncthreads();
      } }
  } // layers

  for (int o=tid; o<5120; o+=TPB){
    int p = o/80, d = o - p*80;
    float v = (d<64) ? sm[O_LAST + p*64 + d] : sm[O_MST + (d-64)*64 + p];
    stf<BF>(outp, (long)b*5120 + o, v);
  }
  for (int o=tid; o<1024; o+=TPB)
    stf<BF>(outp, (long)256*5120 + (long)b*1024 + o, sm[O_MST+o]);
}

// dtype sniffer: an_g ~= 1.0 +- 0.02 in both u16 halves iff bf16 storage.
__global__ void detect_dtype(const void* ang, int* flag){
  if (threadIdx.x == 0 && blockIdx.x == 0){
    const unsigned* w = (const unsigned*)ang;
    int good = 0;
    for (int k=0; k<64; ++k){
      unsigned u = w[k];
      float lo = __builtin_bit_cast(float, (u & 0xFFFFu) << 16);
      float hi = __builtin_bit_cast(float, u & 0xFFFF0000u);
      if (lo > 0.7f && lo < 1.4f && hi > 0.7f && hi < 1.4f) ++good;
    }
    *flag = (good >= 48) ? 1 : 0;
  }
}

__global__ void __launch_bounds__(TPB, 1) converter_kernel(
    const void* x, const void* st, const void* cw4, const void* cw3, const void* cw2,
    const void* cw1, const void* cb, const void* qw, const void* qb, const void* ow,
    const void* ob, const void* ffw, const void* ang, const void* anb, const void* gk,
    const void* grr, const void* gbb, const void* sg, const void* sb2,
    const int* flagp, void* outp, float* bypass)
{
  extern __shared__ float sm[];
  if (*flagp)
    run_all<1>(sm, x, st, cw4, cw3, cw2, cw1, cb, qw, qb, ow, ob, ffw, ang, anb,
               gk, grr, gbb, sg, sb2, outp, bypass);
  else
    run_all<0>(sm, x, st, cw4, cw3, cw2, cw1, cb, qw, qb, ow, ob, ffw, ang, anb,
               gk, grr, gbb, sg, sb2, outp, bypass);
}

extern "C" void kernel_launch(void* const* d_in, const int* in_sizes, int n_in,
                              void* d_out, int out_size, void* d_ws, size_t ws_size,
                              hipStream_t stream) {
  (void)in_sizes; (void)n_in; (void)out_size; (void)ws_size;
  int*   flag   = (int*)d_ws;
  float* bypass = (float*)((char*)d_ws + 256);   // 256*4*4096 f32 = 16.8 MB

  hipFuncSetAttribute(reinterpret_cast<const void*>(converter_kernel),
                      hipFuncAttributeMaxDynamicSharedMemorySize, SMF*4);

  detect_dtype<<<1, 64, 0, stream>>>(d_in[12], flag);
  converter_kernel<<<256, TPB, SMF*4, stream>>>(
      d_in[0], d_in[1], d_in[2], d_in[3], d_in[4], d_in[5], d_in[6], d_in[7],
      d_in[8], d_in[9], d_in[10], d_in[11], d_in[12], d_in[13], d_in[14],
      d_in[15], d_in[16], d_in[17], d_in[18], flag, d_out, bypass);
}